// Round 20
// baseline (138.691 us; speedup 1.0000x reference)
//
#include <hip/hip_runtime.h>
#include <math.h>

#define RMAX 4.0f
#define NTAB 2048    // intervals over [0,4); lerp err ~ (4/NTAB)^2/8 ~ 5e-7 rel
#define DEGCAP 32    // live in-degree ~Poisson(6.9); P(>32)~1e-14 -> exact
#define TR64 65      // 64-wide LDS row stride (bank (lane+j)%32 -> 2-way free)
#define TR32 33      // 32-wide LDS row stride

__device__ __forceinline__ float rcp_fast(float x){
  return __builtin_amdgcn_rcpf(x);   // raw v_rcp_f32, ~1 ulp
}
__device__ __forceinline__ float tanh_fast(float x){
  float e = __expf(2.0f * x);
  return 1.0f - 2.0f * rcp_fast(e + 1.0f);
}
__device__ __forceinline__ float normact(float s){
  float ns = fabsf(s);
  return s * tanh_fast(ns) * rcp_fast(ns + 1e-8f);
}

// ---------------- fused prep: pack | sctab | radial table ----------------
__global__ void __launch_bounds__(256) k_prep(
    const float* __restrict__ coords, const int* __restrict__ species,
    const float* __restrict__ Wna, const float* __restrict__ Wlin1,
    const float* __restrict__ Wsc,
    const float* __restrict__ Wr1, const float* __restrict__ Wr2,
    const float* __restrict__ Wr3,
    float4* __restrict__ packed, float* __restrict__ sctab,
    float* __restrict__ tab, int N, int nPack){
  int b = blockIdx.x;
  int t = threadIdx.x;
  if (b < nPack){                       // ---- pack ----
    int n = b * 256 + t;
    if (n >= N) return;
    float4 v;
    v.x = coords[3*n+0]; v.y = coords[3*n+1]; v.z = coords[3*n+2];
    v.w = __int_as_float(species[n]);
    packed[n] = v;
    return;
  }
  if (b == nPack){                      // ---- sctab ----
    if (t < 256){
      int c = t >> 6, k = t & 63;
      float acc = 0.f;
      for (int i = 0; i < 32; ++i) acc += Wna[c*32+i] * Wsc[(i*4+c)*64+k];
      sctab[t] = acc * (0.5f * 0.08838834764831843f);
    }
    return;
  }
  // ---- radial table ----
  __shared__ float sW1[8*64];
  __shared__ float sW2T[64*64];
  __shared__ float sW3[64*32];
  __shared__ float sX1[4*32];
  for (int i = t; i < 512; i += 256) sW1[i] = Wr1[i] * 0.3535533905932738f;
  for (int i = t; i < 4096; i += 256){ int rr = i >> 6, cc = i & 63; sW2T[cc*64+rr] = Wr2[i] * 0.125f; }
  for (int i = t; i < 2048; i += 256){ int rr = i >> 5, cc = i & 31; sW3[i] = Wr3[rr*64+cc] * 0.125f; }
  if (t < 128){                         // x1tab inline
    int c = t >> 5, j = t & 31;
    float acc = 0.f;
    for (int i = 0; i < 32; ++i) acc += Wna[c*32+i] * Wlin1[i*32+j];
    sX1[t] = acc * (0.5f * 0.17677669529663687f);
  }
  __syncthreads();
  int i = (b - nPack - 1) * 256 + t;
  if (i > NTAB) return;
  float r = fmaxf((float)i * (RMAX / (float)NTAB), 1e-6f);

  float u = r * 0.25f;
  float u2 = u*u, u4 = u2*u2, u6 = u4*u2;
  float fc = 1.0f + u6 * (-28.0f + u * (48.0f - 21.0f * u));
  float pref = 0.5f * rcp_fast(r) * fc;
  float ea[8];
  #pragma unroll
  for (int k = 1; k <= 8; ++k) ea[k-1] = __sinf(0.78539816339744831f * r * (float)k) * pref;

  float h1[64];
  #pragma unroll
  for (int j = 0; j < 64; j += 4){
    float ax = 0.f, ay = 0.f, az = 0.f, aw = 0.f;
    #pragma unroll
    for (int k = 0; k < 8; ++k){
      const float4 w4 = *(const float4*)&sW1[k*64 + j];
      ax += ea[k]*w4.x; ay += ea[k]*w4.y; az += ea[k]*w4.z; aw += ea[k]*w4.w;
    }
    h1[j]   = tanh_fast(ax); h1[j+1] = tanh_fast(ay);
    h1[j+2] = tanh_fast(az); h1[j+3] = tanh_fast(aw);
  }

  float wsx[8], wsy[8], wsz[8], wsw[8];
  #pragma unroll
  for (int g = 0; g < 8; ++g){ wsx[g]=0.f; wsy[g]=0.f; wsz[g]=0.f; wsw[g]=0.f; }
  for (int j = 0; j < 64; ++j){
    float ax = 0.f, ay = 0.f, az = 0.f, aw = 0.f;
    #pragma unroll
    for (int k = 0; k < 64; k += 4){
      const float4 w4 = *(const float4*)&sW2T[j*64 + k];
      ax += h1[k]*w4.x; ay += h1[k+1]*w4.y; az += h1[k+2]*w4.z; aw += h1[k+3]*w4.w;
    }
    float tj = tanh_fast(ax + ay + az + aw);
    #pragma unroll
    for (int g = 0; g < 8; ++g){
      const float4 w4 = *(const float4*)&sW3[j*32 + g*4];
      wsx[g] += tj*w4.x; wsy[g] += tj*w4.y; wsz[g] += tj*w4.z; wsw[g] += tj*w4.w;
    }
  }

  #pragma unroll
  for (int c = 0; c < 4; ++c){
    float* row = tab + ((size_t)i*4 + c)*32;
    #pragma unroll
    for (int g = 0; g < 8; ++g){
      const float4 xv = *(const float4*)&sX1[c*32 + g*4];
      row[g*4+0] = wsx[g]*xv.x;
      row[g*4+1] = wsy[g]*xv.y;
      row[g*4+2] = wsz[g]*xv.z;
      row[g*4+3] = wsw[g]*xv.w;
    }
  }
}

// ---------------- single-pass bucketed edge build ----------------
__global__ void __launch_bounds__(256) k_edges(
    const float4* __restrict__ packed, const int* __restrict__ ei,
    int* __restrict__ hist, unsigned* __restrict__ pay, int E){
  int i = blockIdx.x * blockDim.x + threadIdx.x;
  if (i >= E) return;
  int s = ei[i], d = ei[E + i];
  float4 ps = packed[s];
  float4 pd = packed[d];
  float dx = pd.x - ps.x, dy = pd.y - ps.y, dz = pd.z - ps.z;
  float r2 = dx*dx + dy*dy + dz*dz + 1e-8f;
  if (r2 >= RMAX*RMAX) return;           // fcut=0 -> msg exactly 0
  float r = sqrtf(r2);
  unsigned u = (__float_as_uint(r) & ~3u) | (unsigned)__float_as_int(ps.w);
  int pos = atomicAdd(&hist[d], 1);
  if (pos < DEGCAP) pay[(size_t)d * DEGCAP + pos] = u;
}

// ---------------- fused gather + node tail: 64 nodes/block, 8-wave k-split ----
// Round-19 post-mortem: k_tail stuck at 54us across occupancy 39->56% with
// VALUBusy ~45% -> neither TLP nor VALU. Invariant suspect: 36KB of weights
// s_load'ed per block through the ~16KB K$ (thrash, SQC-serialized, wave-
// count-independent). This round: stage ALL weights (9248 floats, 37KB) into
// LDS once per block via coalesced float4 vector loads; inner loops read
// them as wave-uniform broadcast ds_read (same-address = conflict-free).
// LDS 62.1KB -> 2 blocks/CU; round-19 showed occupancy doesn't matter here.
__global__ void __launch_bounds__(512) k_tail(
    const int* __restrict__ hist, const unsigned* __restrict__ pay,
    const float* __restrict__ tab, const float* __restrict__ sctab,
    const int* __restrict__ species,
    const float* __restrict__ W2s, const float* __restrict__ Wfin,
    const float* __restrict__ Wr,  const float* __restrict__ Wm1,
    const float* __restrict__ Wm2, const float* __restrict__ Wm3,
    float* __restrict__ out, int N){
  const float s_16s32 = 0.0625f * 0.17677669529663687f;
  const float s_s64   = 0.125f;
  const float s_s32   = 0.17677669529663687f;
  __shared__ float b64[64 * TR64];   // 16.64 KB
  __shared__ float b32[64 * TR32];   // 8.45 KB
  __shared__ float wbuf[9248];       // 36.99 KB: W2s|Wfin|Wr|Wm1|Wm2|Wm3
  const int oW2s = 0, oWfin = 2048, oWr = 4096, oWm1 = 5120, oWm2 = 7168, oWm3 = 9216;

  // ---- stage weights: coalesced float4 copies (512 threads) ----
  {
    int t = threadIdx.x;
    float4* dst;
    dst = (float4*)&wbuf[oW2s];
    for (int i = t; i < 512; i += 512) dst[i] = ((const float4*)W2s)[i];
    dst = (float4*)&wbuf[oWfin];
    for (int i = t; i < 512; i += 512) dst[i] = ((const float4*)Wfin)[i];
    dst = (float4*)&wbuf[oWr];
    for (int i = t; i < 256; i += 512) dst[i] = ((const float4*)Wr)[i];
    dst = (float4*)&wbuf[oWm1];
    for (int i = t; i < 512; i += 512) dst[i] = ((const float4*)Wm1)[i];
    dst = (float4*)&wbuf[oWm2];
    for (int i = t; i < 512; i += 512) dst[i] = ((const float4*)Wm2)[i];
    dst = (float4*)&wbuf[oWm3];
    for (int i = t; i < 8; i += 512) dst[i] = ((const float4*)Wm3)[i];
  }

  // ---- Phase G: gather 64 nodes with 512 threads (8 lanes/node) ----
  {
    int nb  = threadIdx.x >> 3;      // node-in-block 0..63
    int sub = threadIdx.x & 7;       // owns comps [sub*4, sub*4+4)
    int ng  = blockIdx.x * 64 + nb;
    int ngc = min(ng, N - 1);
    float4 accA = make_float4(0.f, 0.f, 0.f, 0.f);
    int cnt = min(hist[ngc], DEGCAP);
    const unsigned* prow = pay + (size_t)ngc * DEGCAP;
    const uint4* p4 = (const uint4*)prow;
    uint4 u0 = p4[0], u1 = p4[1];    // always in-bounds (DEGCAP slots exist)
    #define GSTEP(UVAL, EIDX)                                                  \
      if ((EIDX) < cnt){                                                       \
        unsigned uu = (UVAL);                                                  \
        int ccc = (int)(uu & 3u);                                              \
        float r = __uint_as_float(uu & ~3u);                                   \
        float tt = r * ((float)NTAB / RMAX);                                   \
        int i0 = min((int)tt, NTAB - 1);                                       \
        float f = tt - (float)i0;                                              \
        const float4* r0 = (const float4*)(tab + ((size_t)i0*4 + ccc)*32) + sub; \
        float4 p = r0[0], q = r0[32];                                          \
        accA.x += p.x + f*(q.x - p.x);                                         \
        accA.y += p.y + f*(q.y - p.y);                                         \
        accA.z += p.z + f*(q.z - p.z);                                         \
        accA.w += p.w + f*(q.w - p.w);                                         \
      }
    GSTEP(u0.x, 0) GSTEP(u0.y, 1) GSTEP(u0.z, 2) GSTEP(u0.w, 3)
    GSTEP(u1.x, 4) GSTEP(u1.y, 5) GSTEP(u1.z, 6) GSTEP(u1.w, 7)
    for (int e = 8; e < cnt; ++e){ GSTEP(prow[e], e) }
    #undef GSTEP
    *(float4*)&b32[nb * TR32 + sub * 4] = accA;
  }
  __syncthreads();   // covers weight staging + gather writes

  // ---- Tail: lane = node-in-block; wave wu owns its k-slice ----
  int lane = threadIdx.x & 63;
  int wu   = __builtin_amdgcn_readfirstlane(threadIdx.x >> 6);  // 0..7, SGPR
  int n    = blockIdx.x * 64 + lane;
  bool valid = n < N;
  int nc  = valid ? n : (N - 1);
  int c   = species[nc];
  int k8s = wu * 8;    // 64-wide slice offset
  int k4  = wu * 4;    // 32-wide slice offset
  float* rowL = &b64[lane * TR64];
  float* rowS = &b32[lane * TR32];

  // ---- L1: S[64] = normact(a @ W2s * s + sctab[c]); wave owns [k8s,k8s+8) ----
  {
    const float* wL = &wbuf[oW2s + k8s];
    float acc[8];
    #pragma unroll
    for (int t = 0; t < 8; ++t) acc[t] = 0.f;
    #pragma unroll 4
    for (int j = 0; j < 32; ++j){
      float av = rowS[j];
      #pragma unroll
      for (int t = 0; t < 8; ++t) acc[t] += av * wL[j*64 + t];
    }
    #pragma unroll
    for (int t = 0; t < 8; ++t)
      rowL[k8s + t] = normact(acc[t]*s_16s32 + sctab[c*64 + k8s + t]);
  }
  __syncthreads();

  // ---- L2: y[32] = normact(S @ Wfin * s_s64); wave owns [k4,k4+4) ----
  {
    const float* wL = &wbuf[oWfin + k4];
    float acc[4];
    #pragma unroll
    for (int t = 0; t < 4; ++t) acc[t] = 0.f;
    #pragma unroll 4
    for (int j = 0; j < 64; ++j){
      float sv = rowL[j];
      #pragma unroll
      for (int t = 0; t < 4; ++t) acc[t] += sv * wL[j*32 + t];
    }
    #pragma unroll
    for (int t = 0; t < 4; ++t) rowS[k4 + t] = normact(acc[t]*s_s64);
  }
  __syncthreads();

  // ---- L3: y2[32] = y + normact(y @ Wr * s_s32); y2 -> b64[0,32) ----
  {
    const float* wL = &wbuf[oWr + k4];
    float acc[4];
    #pragma unroll
    for (int t = 0; t < 4; ++t) acc[t] = 0.f;
    #pragma unroll 4
    for (int j = 0; j < 32; ++j){
      float yv = rowS[j];
      #pragma unroll
      for (int t = 0; t < 4; ++t) acc[t] += yv * wL[j*32 + t];
    }
    #pragma unroll
    for (int t = 0; t < 4; ++t)
      rowL[k4 + t] = rowS[k4 + t] + normact(acc[t]*s_s32);
  }
  __syncthreads();

  // ---- L4: h[64] = tanh(y2 @ Wm1 * s_s32); waves 0-3 -> b32, 4-7 -> b64[32,64) ----
  {
    const float* wL = &wbuf[oWm1 + k8s];
    float acc[8];
    #pragma unroll
    for (int t = 0; t < 8; ++t) acc[t] = 0.f;
    #pragma unroll 4
    for (int j = 0; j < 32; ++j){
      float yv = rowL[j];
      #pragma unroll
      for (int t = 0; t < 8; ++t) acc[t] += yv * wL[j*64 + t];
    }
    float* hdst = (wu < 4) ? rowS : rowL;   // k8s: 0..24 -> b32 ; 32..56 -> b64
    #pragma unroll
    for (int t = 0; t < 8; ++t) hdst[k8s + t] = tanh_fast(acc[t]*s_s32);
  }
  __syncthreads();

  // ---- L5: g[32] = tanh(h @ Wm2 * s_s64); partial dot with Wm3 -> b64[wu] ----
  {
    const float* wL = &wbuf[oWm2 + k4];
    float acc[4];
    #pragma unroll
    for (int t = 0; t < 4; ++t) acc[t] = 0.f;
    #pragma unroll 4
    for (int j = 0; j < 32; ++j){
      float hv = rowS[j];
      #pragma unroll
      for (int t = 0; t < 4; ++t) acc[t] += hv * wL[j*32 + t];
    }
    #pragma unroll 4
    for (int j = 32; j < 64; ++j){
      float hv = rowL[j];
      #pragma unroll
      for (int t = 0; t < 4; ++t) acc[t] += hv * wL[j*32 + t];
    }
    float part = 0.f;
    #pragma unroll
    for (int t = 0; t < 4; ++t) part += tanh_fast(acc[t]*s_s64) * wbuf[oWm3 + k4 + t];
    rowL[wu] = part;   // b64[0,32) = y2, dead after L4 reads
  }
  __syncthreads();

  if (wu == 0 && valid)
    out[n] = (rowL[0] + rowL[1] + rowL[2] + rowL[3] +
              rowL[4] + rowL[5] + rowL[6] + rowL[7]) * s_s32;
}

extern "C" void kernel_launch(void* const* d_in, const int* in_sizes, int n_in,
                              void* d_out, int out_size, void* d_ws, size_t ws_size,
                              hipStream_t stream) {
  const float* coords   = (const float*)d_in[0];
  const int*   species  = (const int*)  d_in[1];
  const int*   ei       = (const int*)  d_in[2];
  const float* Wna      = (const float*)d_in[4];
  const float* Wlin1    = (const float*)d_in[5];
  const float* Wr1      = (const float*)d_in[6];
  const float* Wr2      = (const float*)d_in[7];
  const float* Wr3      = (const float*)d_in[8];
  const float* W2s      = (const float*)d_in[9];
  const float* Wsc      = (const float*)d_in[11];
  const float* Wfin     = (const float*)d_in[12];
  const float* Wr       = (const float*)d_in[13];
  const float* Wm1      = (const float*)d_in[14];
  const float* Wm2      = (const float*)d_in[15];
  const float* Wm3      = (const float*)d_in[16];
  float* out = (float*)d_out;

  const int N = in_sizes[1];
  const int E = in_sizes[2] / 2;

  char* ws = (char*)d_ws;
  size_t offSC  = 0;                                 // sctab 1024B
  size_t offTAB = offSC + 1024;                      // tab (NTAB+2)*128 f32 (~1.05MB)
  size_t offH   = offTAB + (size_t)(NTAB+2)*128*4;   // hist [N] int
  size_t offP   = offH + (size_t)N*4;                // pay  [N*DEGCAP] u32 (12.8MB)
  size_t offPK  = offP + (size_t)N*DEGCAP*4;         // packed [N] float4 (1.6MB)

  float*    sctab = (float*)(ws + offSC);
  float*    tab   = (float*)(ws + offTAB);
  int*      hist  = (int*)  (ws + offH);
  unsigned* pay   = (unsigned*)(ws + offP);
  float4*   packed= (float4*)(ws + offPK);

  hipMemsetAsync(hist, 0, (size_t)N*4, stream);

  int nPack = (N + 255) / 256;
  int nTab  = (NTAB + 1 + 255) / 256;
  k_prep<<<nPack + 1 + nTab, 256, 0, stream>>>(coords, species, Wna, Wlin1, Wsc,
                                               Wr1, Wr2, Wr3, packed, sctab, tab,
                                               N, nPack);
  k_edges<<<(E + 255) / 256, 256, 0, stream>>>(packed, ei, hist, pay, E);
  k_tail<<<(N + 63) / 64, 512, 0, stream>>>(hist, pay, tab, sctab, species,
                                            W2s, Wfin, Wr, Wm1, Wm2, Wm3, out, N);
}

// Round 23
// 127.162 us; speedup vs baseline: 1.0907x; 1.0907x over previous
//
#include <hip/hip_runtime.h>
#include <math.h>

#define RMAX 4.0f
#define NTAB 2048    // intervals over [0,4); lerp err ~ (4/NTAB)^2/8 ~ 5e-7 rel
#define DEGCAP 32    // live in-degree ~Poisson(6.9); P(>32)~1e-14 -> exact
#define TR64 68      // 64-wide LDS row stride: 272B = 16B-aligned
#define TR32 36      // 32-wide LDS row stride: 144B = 16B-aligned

__device__ __forceinline__ float rcp_fast(float x){
  return __builtin_amdgcn_rcpf(x);   // raw v_rcp_f32, ~1 ulp
}
__device__ __forceinline__ float tanh_fast(float x){
  float e = __expf(2.0f * x);
  return 1.0f - 2.0f * rcp_fast(e + 1.0f);
}
__device__ __forceinline__ float normact(float s){
  float ns = fabsf(s);
  return s * tanh_fast(ns) * rcp_fast(ns + 1e-8f);
}

// ---------------- fused prep: pack | sctab | radial table ----------------
__global__ void __launch_bounds__(256) k_prep(
    const float* __restrict__ coords, const int* __restrict__ species,
    const float* __restrict__ Wna, const float* __restrict__ Wlin1,
    const float* __restrict__ Wsc,
    const float* __restrict__ Wr1, const float* __restrict__ Wr2,
    const float* __restrict__ Wr3,
    float4* __restrict__ packed, float* __restrict__ sctab,
    float* __restrict__ tab, int N, int nPack){
  int b = blockIdx.x;
  int t = threadIdx.x;
  if (b < nPack){                       // ---- pack ----
    int n = b * 256 + t;
    if (n >= N) return;
    float4 v;
    v.x = coords[3*n+0]; v.y = coords[3*n+1]; v.z = coords[3*n+2];
    v.w = __int_as_float(species[n]);
    packed[n] = v;
    return;
  }
  if (b == nPack){                      // ---- sctab ----
    if (t < 256){
      int c = t >> 6, k = t & 63;
      float acc = 0.f;
      for (int i = 0; i < 32; ++i) acc += Wna[c*32+i] * Wsc[(i*4+c)*64+k];
      sctab[t] = acc * (0.5f * 0.08838834764831843f);
    }
    return;
  }
  // ---- radial table ----
  __shared__ float sW1[8*64];
  __shared__ float sW2T[64*64];
  __shared__ float sW3[64*32];
  __shared__ float sX1[4*32];
  for (int i = t; i < 512; i += 256) sW1[i] = Wr1[i] * 0.3535533905932738f;
  for (int i = t; i < 4096; i += 256){ int rr = i >> 6, cc = i & 63; sW2T[cc*64+rr] = Wr2[i] * 0.125f; }
  for (int i = t; i < 2048; i += 256){ int rr = i >> 5, cc = i & 31; sW3[i] = Wr3[rr*64+cc] * 0.125f; }
  if (t < 128){                         // x1tab inline
    int c = t >> 5, j = t & 31;
    float acc = 0.f;
    for (int i = 0; i < 32; ++i) acc += Wna[c*32+i] * Wlin1[i*32+j];
    sX1[t] = acc * (0.5f * 0.17677669529663687f);
  }
  __syncthreads();
  int i = (b - nPack - 1) * 256 + t;
  if (i > NTAB) return;
  float r = fmaxf((float)i * (RMAX / (float)NTAB), 1e-6f);

  float u = r * 0.25f;
  float u2 = u*u, u4 = u2*u2, u6 = u4*u2;
  float fc = 1.0f + u6 * (-28.0f + u * (48.0f - 21.0f * u));
  float pref = 0.5f * rcp_fast(r) * fc;
  float ea[8];
  #pragma unroll
  for (int k = 1; k <= 8; ++k) ea[k-1] = __sinf(0.78539816339744831f * r * (float)k) * pref;

  float h1[64];
  #pragma unroll
  for (int j = 0; j < 64; j += 4){
    float ax = 0.f, ay = 0.f, az = 0.f, aw = 0.f;
    #pragma unroll
    for (int k = 0; k < 8; ++k){
      const float4 w4 = *(const float4*)&sW1[k*64 + j];
      ax += ea[k]*w4.x; ay += ea[k]*w4.y; az += ea[k]*w4.z; aw += ea[k]*w4.w;
    }
    h1[j]   = tanh_fast(ax); h1[j+1] = tanh_fast(ay);
    h1[j+2] = tanh_fast(az); h1[j+3] = tanh_fast(aw);
  }

  float wsx[8], wsy[8], wsz[8], wsw[8];
  #pragma unroll
  for (int g = 0; g < 8; ++g){ wsx[g]=0.f; wsy[g]=0.f; wsz[g]=0.f; wsw[g]=0.f; }
  for (int j = 0; j < 64; ++j){
    float ax = 0.f, ay = 0.f, az = 0.f, aw = 0.f;
    #pragma unroll
    for (int k = 0; k < 64; k += 4){
      const float4 w4 = *(const float4*)&sW2T[j*64 + k];
      ax += h1[k]*w4.x; ay += h1[k+1]*w4.y; az += h1[k+2]*w4.z; aw += h1[k+3]*w4.w;
    }
    float tj = tanh_fast(ax + ay + az + aw);
    #pragma unroll
    for (int g = 0; g < 8; ++g){
      const float4 w4 = *(const float4*)&sW3[j*32 + g*4];
      wsx[g] += tj*w4.x; wsy[g] += tj*w4.y; wsz[g] += tj*w4.z; wsw[g] += tj*w4.w;
    }
  }

  #pragma unroll
  for (int c = 0; c < 4; ++c){
    float* row = tab + ((size_t)i*4 + c)*32;
    #pragma unroll
    for (int g = 0; g < 8; ++g){
      const float4 xv = *(const float4*)&sX1[c*32 + g*4];
      row[g*4+0] = wsx[g]*xv.x;
      row[g*4+1] = wsy[g]*xv.y;
      row[g*4+2] = wsz[g]*xv.z;
      row[g*4+3] = wsw[g]*xv.w;
    }
  }
}

// ---------------- single-pass bucketed edge build ----------------
__global__ void __launch_bounds__(256) k_edges(
    const float4* __restrict__ packed, const int* __restrict__ ei,
    int* __restrict__ hist, unsigned* __restrict__ pay, int E){
  int i = blockIdx.x * blockDim.x + threadIdx.x;
  if (i >= E) return;
  int s = ei[i], d = ei[E + i];
  float4 ps = packed[s];
  float4 pd = packed[d];
  float dx = pd.x - ps.x, dy = pd.y - ps.y, dz = pd.z - ps.z;
  float r2 = dx*dx + dy*dy + dz*dz + 1e-8f;
  if (r2 >= RMAX*RMAX) return;           // fcut=0 -> msg exactly 0
  float r = sqrtf(r2);
  unsigned u = (__float_as_uint(r) & ~3u) | (unsigned)__float_as_int(ps.w);
  int pos = atomicAdd(&hist[d], 1);
  if (pos < DEGCAP) pay[(size_t)d * DEGCAP + pos] = u;
}

// ---------------- fused gather + node tail: 64 nodes/block, 8-wave k-split ----
// Round-19/20 evidence isolates the LDS ISSUE PORT: 224 scalar ds_read_b32
// per lane = ~12K cyc/block of LDS-unit time = the missing ~30us. This
// round: ALL activation LDS traffic as b128 (float4) -> 56 reads + 6 writes
// per lane, strides 68/36 floats (16B-aligned rows). Weights stay on the
// scalar s_load path (readfirstlane wave-id). LDS 26.6KB, 6 blk/CU.
__global__ void __launch_bounds__(512, 8) k_tail(
    const int* __restrict__ hist, const unsigned* __restrict__ pay,
    const float* __restrict__ tab, const float* __restrict__ sctab,
    const int* __restrict__ species,
    const float* __restrict__ W2s, const float* __restrict__ Wfin,
    const float* __restrict__ Wr,  const float* __restrict__ Wm1,
    const float* __restrict__ Wm2, const float* __restrict__ Wm3,
    float* __restrict__ out, int N){
  const float s_16s32 = 0.0625f * 0.17677669529663687f;
  const float s_s64   = 0.125f;
  const float s_s32   = 0.17677669529663687f;
  __shared__ float b64[64 * TR64];   // 17.41 KB
  __shared__ float b32[64 * TR32];   // 9.22 KB

  // ---- Phase G: gather 64 nodes with 512 threads (8 lanes/node) ----
  {
    int nb  = threadIdx.x >> 3;      // node-in-block 0..63
    int sub = threadIdx.x & 7;       // owns comps [sub*4, sub*4+4)
    int ng  = blockIdx.x * 64 + nb;
    int ngc = min(ng, N - 1);
    float4 accA = make_float4(0.f, 0.f, 0.f, 0.f);
    int cnt = min(hist[ngc], DEGCAP);
    const unsigned* prow = pay + (size_t)ngc * DEGCAP;
    const uint4* p4 = (const uint4*)prow;
    uint4 u0 = p4[0], u1 = p4[1];    // always in-bounds (DEGCAP slots exist)
    #define GSTEP(UVAL, EIDX)                                                  \
      if ((EIDX) < cnt){                                                       \
        unsigned uu = (UVAL);                                                  \
        int ccc = (int)(uu & 3u);                                              \
        float r = __uint_as_float(uu & ~3u);                                   \
        float tt = r * ((float)NTAB / RMAX);                                   \
        int i0 = min((int)tt, NTAB - 1);                                       \
        float f = tt - (float)i0;                                              \
        const float4* r0 = (const float4*)(tab + ((size_t)i0*4 + ccc)*32) + sub; \
        float4 p = r0[0], q = r0[32];                                          \
        accA.x += p.x + f*(q.x - p.x);                                         \
        accA.y += p.y + f*(q.y - p.y);                                         \
        accA.z += p.z + f*(q.z - p.z);                                         \
        accA.w += p.w + f*(q.w - p.w);                                         \
      }
    GSTEP(u0.x, 0) GSTEP(u0.y, 1) GSTEP(u0.z, 2) GSTEP(u0.w, 3)
    GSTEP(u1.x, 4) GSTEP(u1.y, 5) GSTEP(u1.z, 6) GSTEP(u1.w, 7)
    for (int e = 8; e < cnt; ++e){ GSTEP(prow[e], e) }
    #undef GSTEP
    *(float4*)&b32[nb * TR32 + sub * 4] = accA;
  }
  __syncthreads();

  // ---- Tail: lane = node-in-block; wave wu owns its k-slice ----
  int lane = threadIdx.x & 63;
  int wu   = __builtin_amdgcn_readfirstlane(threadIdx.x >> 6);  // 0..7, SGPR
  int n    = blockIdx.x * 64 + lane;
  bool valid = n < N;
  int nc  = valid ? n : (N - 1);
  int c   = species[nc];
  int k8s = wu * 8;    // 64-wide slice offset
  int k4  = wu * 4;    // 32-wide slice offset
  float* rowL = &b64[lane * TR64];
  float* rowS = &b32[lane * TR32];

  // ---- L1: S[64] = normact(a @ W2s * s + sctab[c]); wave owns [k8s,k8s+8) ----
  {
    float acc[8];
    #pragma unroll
    for (int t = 0; t < 8; ++t) acc[t] = 0.f;
    #pragma unroll 4
    for (int j4 = 0; j4 < 8; ++j4){
      float4 a4 = *(const float4*)&rowS[j4*4];
      #pragma unroll
      for (int q = 0; q < 4; ++q){
        float av = (q==0)?a4.x:(q==1)?a4.y:(q==2)?a4.z:a4.w;
        const int j = j4*4 + q;
        #pragma unroll
        for (int t = 0; t < 8; ++t) acc[t] += av * W2s[j*64 + k8s + t];
      }
    }
    float o[8];
    #pragma unroll
    for (int t = 0; t < 8; ++t)
      o[t] = normact(acc[t]*s_16s32 + sctab[c*64 + k8s + t]);
    *(float4*)&rowL[k8s]     = make_float4(o[0], o[1], o[2], o[3]);
    *(float4*)&rowL[k8s + 4] = make_float4(o[4], o[5], o[6], o[7]);
  }
  __syncthreads();

  // ---- L2: y[32] = normact(S @ Wfin * s_s64); wave owns [k4,k4+4) ----
  {
    float acc[4];
    #pragma unroll
    for (int t = 0; t < 4; ++t) acc[t] = 0.f;
    #pragma unroll 4
    for (int j4 = 0; j4 < 16; ++j4){
      float4 s4 = *(const float4*)&rowL[j4*4];
      #pragma unroll
      for (int q = 0; q < 4; ++q){
        float sv = (q==0)?s4.x:(q==1)?s4.y:(q==2)?s4.z:s4.w;
        const int j = j4*4 + q;
        #pragma unroll
        for (int t = 0; t < 4; ++t) acc[t] += sv * Wfin[j*32 + k4 + t];
      }
    }
    *(float4*)&rowS[k4] = make_float4(normact(acc[0]*s_s64), normact(acc[1]*s_s64),
                                      normact(acc[2]*s_s64), normact(acc[3]*s_s64));
  }
  __syncthreads();

  // ---- L3: y2[32] = y + normact(y @ Wr * s_s32); y2 -> b64[0,32) ----
  {
    float acc[4];
    #pragma unroll
    for (int t = 0; t < 4; ++t) acc[t] = 0.f;
    #pragma unroll 4
    for (int j4 = 0; j4 < 8; ++j4){
      float4 y4 = *(const float4*)&rowS[j4*4];
      #pragma unroll
      for (int q = 0; q < 4; ++q){
        float yv = (q==0)?y4.x:(q==1)?y4.y:(q==2)?y4.z:y4.w;
        const int j = j4*4 + q;
        #pragma unroll
        for (int t = 0; t < 4; ++t) acc[t] += yv * Wr[j*32 + k4 + t];
      }
    }
    float4 ysave = *(const float4*)&rowS[k4];
    *(float4*)&rowL[k4] = make_float4(ysave.x + normact(acc[0]*s_s32),
                                      ysave.y + normact(acc[1]*s_s32),
                                      ysave.z + normact(acc[2]*s_s32),
                                      ysave.w + normact(acc[3]*s_s32));
  }
  __syncthreads();

  // ---- L4: h[64] = tanh(y2 @ Wm1 * s_s32); waves 0-3 -> b32, 4-7 -> b64[32,64) ----
  {
    float acc[8];
    #pragma unroll
    for (int t = 0; t < 8; ++t) acc[t] = 0.f;
    #pragma unroll 4
    for (int j4 = 0; j4 < 8; ++j4){
      float4 y4 = *(const float4*)&rowL[j4*4];
      #pragma unroll
      for (int q = 0; q < 4; ++q){
        float yv = (q==0)?y4.x:(q==1)?y4.y:(q==2)?y4.z:y4.w;
        const int j = j4*4 + q;
        #pragma unroll
        for (int t = 0; t < 8; ++t) acc[t] += yv * Wm1[j*64 + k8s + t];
      }
    }
    float* hdst = (wu < 4) ? rowS : rowL;   // k8s: 0..24 -> b32 ; 32..56 -> b64
    float o[8];
    #pragma unroll
    for (int t = 0; t < 8; ++t) o[t] = tanh_fast(acc[t]*s_s32);
    *(float4*)&hdst[k8s]     = make_float4(o[0], o[1], o[2], o[3]);
    *(float4*)&hdst[k8s + 4] = make_float4(o[4], o[5], o[6], o[7]);
  }
  __syncthreads();

  // ---- L5: g[32] = tanh(h @ Wm2 * s_s64); partial dot with Wm3 -> b64[wu] ----
  {
    float acc[4];
    #pragma unroll
    for (int t = 0; t < 4; ++t) acc[t] = 0.f;
    #pragma unroll 4
    for (int j4 = 0; j4 < 8; ++j4){            // h lo: b32[0,32)
      float4 h4 = *(const float4*)&rowS[j4*4];
      #pragma unroll
      for (int q = 0; q < 4; ++q){
        float hv = (q==0)?h4.x:(q==1)?h4.y:(q==2)?h4.z:h4.w;
        const int j = j4*4 + q;
        #pragma unroll
        for (int t = 0; t < 4; ++t) acc[t] += hv * Wm2[j*32 + k4 + t];
      }
    }
    #pragma unroll 4
    for (int j4 = 0; j4 < 8; ++j4){            // h hi: b64[32,64)
      float4 h4 = *(const float4*)&rowL[32 + j4*4];
      #pragma unroll
      for (int q = 0; q < 4; ++q){
        float hv = (q==0)?h4.x:(q==1)?h4.y:(q==2)?h4.z:h4.w;
        const int j = 32 + j4*4 + q;
        #pragma unroll
        for (int t = 0; t < 4; ++t) acc[t] += hv * Wm2[j*32 + k4 + t];
      }
    }
    float part = 0.f;
    #pragma unroll
    for (int t = 0; t < 4; ++t) part += tanh_fast(acc[t]*s_s64) * Wm3[k4 + t];
    rowL[wu] = part;   // b64[0,32) = y2, dead after L4 reads
  }
  __syncthreads();

  if (wu == 0 && valid){
    float4 p0 = *(const float4*)&rowL[0];
    float4 p1 = *(const float4*)&rowL[4];
    out[n] = (p0.x + p0.y + p0.z + p0.w + p1.x + p1.y + p1.z + p1.w) * s_s32;
  }
}

extern "C" void kernel_launch(void* const* d_in, const int* in_sizes, int n_in,
                              void* d_out, int out_size, void* d_ws, size_t ws_size,
                              hipStream_t stream) {
  const float* coords   = (const float*)d_in[0];
  const int*   species  = (const int*)  d_in[1];
  const int*   ei       = (const int*)  d_in[2];
  const float* Wna      = (const float*)d_in[4];
  const float* Wlin1    = (const float*)d_in[5];
  const float* Wr1      = (const float*)d_in[6];
  const float* Wr2      = (const float*)d_in[7];
  const float* Wr3      = (const float*)d_in[8];
  const float* W2s      = (const float*)d_in[9];
  const float* Wsc      = (const float*)d_in[11];
  const float* Wfin     = (const float*)d_in[12];
  const float* Wr       = (const float*)d_in[13];
  const float* Wm1      = (const float*)d_in[14];
  const float* Wm2      = (const float*)d_in[15];
  const float* Wm3      = (const float*)d_in[16];
  float* out = (float*)d_out;

  const int N = in_sizes[1];
  const int E = in_sizes[2] / 2;

  char* ws = (char*)d_ws;
  size_t offSC  = 0;                                 // sctab 1024B
  size_t offTAB = offSC + 1024;                      // tab (NTAB+2)*128 f32 (~1.05MB)
  size_t offH   = offTAB + (size_t)(NTAB+2)*128*4;   // hist [N] int
  size_t offP   = offH + (size_t)N*4;                // pay  [N*DEGCAP] u32 (12.8MB)
  size_t offPK  = offP + (size_t)N*DEGCAP*4;         // packed [N] float4 (1.6MB)

  float*    sctab = (float*)(ws + offSC);
  float*    tab   = (float*)(ws + offTAB);
  int*      hist  = (int*)  (ws + offH);
  unsigned* pay   = (unsigned*)(ws + offP);
  float4*   packed= (float4*)(ws + offPK);

  hipMemsetAsync(hist, 0, (size_t)N*4, stream);

  int nPack = (N + 255) / 256;
  int nTab  = (NTAB + 1 + 255) / 256;
  k_prep<<<nPack + 1 + nTab, 256, 0, stream>>>(coords, species, Wna, Wlin1, Wsc,
                                               Wr1, Wr2, Wr3, packed, sctab, tab,
                                               N, nPack);
  k_edges<<<(E + 255) / 256, 256, 0, stream>>>(packed, ei, hist, pay, E);
  k_tail<<<(N + 63) / 64, 512, 0, stream>>>(hist, pay, tab, sctab, species,
                                            W2s, Wfin, Wr, Wm1, Wm2, Wm3, out, N);
}

// Round 24
// 101.263 us; speedup vs baseline: 1.3696x; 1.2558x over previous
//
#include <hip/hip_runtime.h>
#include <math.h>

#define RMAX 4.0f
#define NTAB 2048    // intervals over [0,4); lerp err ~ (4/NTAB)^2/8 ~ 5e-7 rel
#define DEGCAP 32    // live in-degree ~Poisson(6.9); P(>32)~1e-14 -> exact
#define TR64 68      // 64-wide LDS row stride: 272B = 16B-aligned
#define TR32 36      // 32-wide LDS row stride: 144B = 16B-aligned

__device__ __forceinline__ float rcp_fast(float x){
  return __builtin_amdgcn_rcpf(x);   // raw v_rcp_f32, ~1 ulp
}
__device__ __forceinline__ float tanh_fast(float x){
  float e = __expf(2.0f * x);
  return 1.0f - 2.0f * rcp_fast(e + 1.0f);
}
__device__ __forceinline__ float normact(float s){
  float ns = fabsf(s);
  return s * tanh_fast(ns) * rcp_fast(ns + 1e-8f);
}

// ---------------- pack (x,y,z,species) per node ----------------
__global__ void __launch_bounds__(256) k_pack(
    const float* __restrict__ coords, const int* __restrict__ species,
    float4* __restrict__ packed, int N){
  int n = blockIdx.x * 256 + threadIdx.x;
  if (n >= N) return;
  float4 v;
  v.x = coords[3*n+0]; v.y = coords[3*n+1]; v.z = coords[3*n+2];
  v.w = __int_as_float(species[n]);
  packed[n] = v;
}

// ---------------- fused: radial table | sctab | edge build ----------------
// blocks [0,nTab): tab rows (long-running, dispatched first -> overlap edges)
// block  nTab:     sctab
// blocks >nTab:    bucketed edge build (pay[d*DEGCAP+slot] = r|species(src))
// tab/sctab have NO dependency on edges -> safe concurrency in one launch.
__global__ void __launch_bounds__(256) k_fused(
    const float4* __restrict__ packed, const int* __restrict__ ei,
    int* __restrict__ hist, unsigned* __restrict__ pay, int E,
    const float* __restrict__ Wna, const float* __restrict__ Wlin1,
    const float* __restrict__ Wsc,
    const float* __restrict__ Wr1, const float* __restrict__ Wr2,
    const float* __restrict__ Wr3,
    float* __restrict__ sctab, float* __restrict__ tab, int nTab){
  __shared__ float sW1[8*64];
  __shared__ float sW2T[64*64];
  __shared__ float sW3[64*32];
  __shared__ float sX1[4*32];
  int b = blockIdx.x;
  int t = threadIdx.x;

  if (b > nTab){                        // ---- edges ----
    int i = (b - nTab - 1) * 256 + t;
    if (i >= E) return;
    int s = ei[i], d = ei[E + i];
    float4 ps = packed[s];
    float4 pd = packed[d];
    float dx = pd.x - ps.x, dy = pd.y - ps.y, dz = pd.z - ps.z;
    float r2 = dx*dx + dy*dy + dz*dz + 1e-8f;
    if (r2 >= RMAX*RMAX) return;        // fcut=0 -> msg exactly 0
    float r = sqrtf(r2);
    unsigned u = (__float_as_uint(r) & ~3u) | (unsigned)__float_as_int(ps.w);
    int pos = atomicAdd(&hist[d], 1);
    if (pos < DEGCAP) pay[(size_t)d * DEGCAP + pos] = u;
    return;
  }
  if (b == nTab){                       // ---- sctab ----
    if (t < 256){
      int c = t >> 6, k = t & 63;
      float acc = 0.f;
      for (int i = 0; i < 32; ++i) acc += Wna[c*32+i] * Wsc[(i*4+c)*64+k];
      sctab[t] = acc * (0.5f * 0.08838834764831843f);
    }
    return;
  }
  // ---- radial table ----
  for (int i = t; i < 512; i += 256) sW1[i] = Wr1[i] * 0.3535533905932738f;
  for (int i = t; i < 4096; i += 256){ int rr = i >> 6, cc = i & 63; sW2T[cc*64+rr] = Wr2[i] * 0.125f; }
  for (int i = t; i < 2048; i += 256){ int rr = i >> 5, cc = i & 31; sW3[i] = Wr3[rr*64+cc] * 0.125f; }
  if (t < 128){                         // x1tab inline
    int c = t >> 5, j = t & 31;
    float acc = 0.f;
    for (int i = 0; i < 32; ++i) acc += Wna[c*32+i] * Wlin1[i*32+j];
    sX1[t] = acc * (0.5f * 0.17677669529663687f);
  }
  __syncthreads();
  int i = b * 256 + t;
  if (i > NTAB) return;
  float r = fmaxf((float)i * (RMAX / (float)NTAB), 1e-6f);

  float u = r * 0.25f;
  float u2 = u*u, u4 = u2*u2, u6 = u4*u2;
  float fc = 1.0f + u6 * (-28.0f + u * (48.0f - 21.0f * u));
  float pref = 0.5f * rcp_fast(r) * fc;
  float ea[8];
  #pragma unroll
  for (int k = 1; k <= 8; ++k) ea[k-1] = __sinf(0.78539816339744831f * r * (float)k) * pref;

  float h1[64];
  #pragma unroll
  for (int j = 0; j < 64; j += 4){
    float ax = 0.f, ay = 0.f, az = 0.f, aw = 0.f;
    #pragma unroll
    for (int k = 0; k < 8; ++k){
      const float4 w4 = *(const float4*)&sW1[k*64 + j];
      ax += ea[k]*w4.x; ay += ea[k]*w4.y; az += ea[k]*w4.z; aw += ea[k]*w4.w;
    }
    h1[j]   = tanh_fast(ax); h1[j+1] = tanh_fast(ay);
    h1[j+2] = tanh_fast(az); h1[j+3] = tanh_fast(aw);
  }

  float wsx[8], wsy[8], wsz[8], wsw[8];
  #pragma unroll
  for (int g = 0; g < 8; ++g){ wsx[g]=0.f; wsy[g]=0.f; wsz[g]=0.f; wsw[g]=0.f; }
  for (int j = 0; j < 64; ++j){
    float ax = 0.f, ay = 0.f, az = 0.f, aw = 0.f;
    #pragma unroll
    for (int k = 0; k < 64; k += 4){
      const float4 w4 = *(const float4*)&sW2T[j*64 + k];
      ax += h1[k]*w4.x; ay += h1[k+1]*w4.y; az += h1[k+2]*w4.z; aw += h1[k+3]*w4.w;
    }
    float tj = tanh_fast(ax + ay + az + aw);
    #pragma unroll
    for (int g = 0; g < 8; ++g){
      const float4 w4 = *(const float4*)&sW3[j*32 + g*4];
      wsx[g] += tj*w4.x; wsy[g] += tj*w4.y; wsz[g] += tj*w4.z; wsw[g] += tj*w4.w;
    }
  }

  #pragma unroll
  for (int c = 0; c < 4; ++c){
    float* row = tab + ((size_t)i*4 + c)*32;
    #pragma unroll
    for (int g = 0; g < 8; ++g){
      const float4 xv = *(const float4*)&sX1[c*32 + g*4];
      row[g*4+0] = wsx[g]*xv.x;
      row[g*4+1] = wsy[g]*xv.y;
      row[g*4+2] = wsz[g]*xv.z;
      row[g*4+3] = wsw[g]*xv.w;
    }
  }
}

// ---------------- fused gather + node tail: 64 nodes/block, 8-wave k-split ----
// k_tail structure frozen (round-23 b128 form): wall invariant ~54us across
// five structures; VALUBusy 55%, occupancy 57%. Serial phase-latency floor.
__global__ void __launch_bounds__(512, 8) k_tail(
    const int* __restrict__ hist, const unsigned* __restrict__ pay,
    const float* __restrict__ tab, const float* __restrict__ sctab,
    const int* __restrict__ species,
    const float* __restrict__ W2s, const float* __restrict__ Wfin,
    const float* __restrict__ Wr,  const float* __restrict__ Wm1,
    const float* __restrict__ Wm2, const float* __restrict__ Wm3,
    float* __restrict__ out, int N){
  const float s_16s32 = 0.0625f * 0.17677669529663687f;
  const float s_s64   = 0.125f;
  const float s_s32   = 0.17677669529663687f;
  __shared__ float b64[64 * TR64];   // 17.41 KB
  __shared__ float b32[64 * TR32];   // 9.22 KB

  // ---- Phase G: gather 64 nodes with 512 threads (8 lanes/node) ----
  {
    int nb  = threadIdx.x >> 3;      // node-in-block 0..63
    int sub = threadIdx.x & 7;       // owns comps [sub*4, sub*4+4)
    int ng  = blockIdx.x * 64 + nb;
    int ngc = min(ng, N - 1);
    float4 accA = make_float4(0.f, 0.f, 0.f, 0.f);
    int cnt = min(hist[ngc], DEGCAP);
    const unsigned* prow = pay + (size_t)ngc * DEGCAP;
    const uint4* p4 = (const uint4*)prow;
    uint4 u0 = p4[0], u1 = p4[1];    // always in-bounds (DEGCAP slots exist)
    #define GSTEP(UVAL, EIDX)                                                  \
      if ((EIDX) < cnt){                                                       \
        unsigned uu = (UVAL);                                                  \
        int ccc = (int)(uu & 3u);                                              \
        float r = __uint_as_float(uu & ~3u);                                   \
        float tt = r * ((float)NTAB / RMAX);                                   \
        int i0 = min((int)tt, NTAB - 1);                                       \
        float f = tt - (float)i0;                                              \
        const float4* r0 = (const float4*)(tab + ((size_t)i0*4 + ccc)*32) + sub; \
        float4 p = r0[0], q = r0[32];                                          \
        accA.x += p.x + f*(q.x - p.x);                                         \
        accA.y += p.y + f*(q.y - p.y);                                         \
        accA.z += p.z + f*(q.z - p.z);                                         \
        accA.w += p.w + f*(q.w - p.w);                                         \
      }
    GSTEP(u0.x, 0) GSTEP(u0.y, 1) GSTEP(u0.z, 2) GSTEP(u0.w, 3)
    GSTEP(u1.x, 4) GSTEP(u1.y, 5) GSTEP(u1.z, 6) GSTEP(u1.w, 7)
    for (int e = 8; e < cnt; ++e){ GSTEP(prow[e], e) }
    #undef GSTEP
    *(float4*)&b32[nb * TR32 + sub * 4] = accA;
  }
  __syncthreads();

  // ---- Tail: lane = node-in-block; wave wu owns its k-slice ----
  int lane = threadIdx.x & 63;
  int wu   = __builtin_amdgcn_readfirstlane(threadIdx.x >> 6);  // 0..7, SGPR
  int n    = blockIdx.x * 64 + lane;
  bool valid = n < N;
  int nc  = valid ? n : (N - 1);
  int c   = species[nc];
  int k8s = wu * 8;    // 64-wide slice offset
  int k4  = wu * 4;    // 32-wide slice offset
  float* rowL = &b64[lane * TR64];
  float* rowS = &b32[lane * TR32];

  // ---- L1: S[64] = normact(a @ W2s * s + sctab[c]); wave owns [k8s,k8s+8) ----
  {
    float acc[8];
    #pragma unroll
    for (int t = 0; t < 8; ++t) acc[t] = 0.f;
    #pragma unroll 4
    for (int j4 = 0; j4 < 8; ++j4){
      float4 a4 = *(const float4*)&rowS[j4*4];
      #pragma unroll
      for (int q = 0; q < 4; ++q){
        float av = (q==0)?a4.x:(q==1)?a4.y:(q==2)?a4.z:a4.w;
        const int j = j4*4 + q;
        #pragma unroll
        for (int t = 0; t < 8; ++t) acc[t] += av * W2s[j*64 + k8s + t];
      }
    }
    float o[8];
    #pragma unroll
    for (int t = 0; t < 8; ++t)
      o[t] = normact(acc[t]*s_16s32 + sctab[c*64 + k8s + t]);
    *(float4*)&rowL[k8s]     = make_float4(o[0], o[1], o[2], o[3]);
    *(float4*)&rowL[k8s + 4] = make_float4(o[4], o[5], o[6], o[7]);
  }
  __syncthreads();

  // ---- L2: y[32] = normact(S @ Wfin * s_s64); wave owns [k4,k4+4) ----
  {
    float acc[4];
    #pragma unroll
    for (int t = 0; t < 4; ++t) acc[t] = 0.f;
    #pragma unroll 4
    for (int j4 = 0; j4 < 16; ++j4){
      float4 s4 = *(const float4*)&rowL[j4*4];
      #pragma unroll
      for (int q = 0; q < 4; ++q){
        float sv = (q==0)?s4.x:(q==1)?s4.y:(q==2)?s4.z:s4.w;
        const int j = j4*4 + q;
        #pragma unroll
        for (int t = 0; t < 4; ++t) acc[t] += sv * Wfin[j*32 + k4 + t];
      }
    }
    *(float4*)&rowS[k4] = make_float4(normact(acc[0]*s_s64), normact(acc[1]*s_s64),
                                      normact(acc[2]*s_s64), normact(acc[3]*s_s64));
  }
  __syncthreads();

  // ---- L3: y2[32] = y + normact(y @ Wr * s_s32); y2 -> b64[0,32) ----
  {
    float acc[4];
    #pragma unroll
    for (int t = 0; t < 4; ++t) acc[t] = 0.f;
    #pragma unroll 4
    for (int j4 = 0; j4 < 8; ++j4){
      float4 y4 = *(const float4*)&rowS[j4*4];
      #pragma unroll
      for (int q = 0; q < 4; ++q){
        float yv = (q==0)?y4.x:(q==1)?y4.y:(q==2)?y4.z:y4.w;
        const int j = j4*4 + q;
        #pragma unroll
        for (int t = 0; t < 4; ++t) acc[t] += yv * Wr[j*32 + k4 + t];
      }
    }
    float4 ysave = *(const float4*)&rowS[k4];
    *(float4*)&rowL[k4] = make_float4(ysave.x + normact(acc[0]*s_s32),
                                      ysave.y + normact(acc[1]*s_s32),
                                      ysave.z + normact(acc[2]*s_s32),
                                      ysave.w + normact(acc[3]*s_s32));
  }
  __syncthreads();

  // ---- L4: h[64] = tanh(y2 @ Wm1 * s_s32); waves 0-3 -> b32, 4-7 -> b64[32,64) ----
  {
    float acc[8];
    #pragma unroll
    for (int t = 0; t < 8; ++t) acc[t] = 0.f;
    #pragma unroll 4
    for (int j4 = 0; j4 < 8; ++j4){
      float4 y4 = *(const float4*)&rowL[j4*4];
      #pragma unroll
      for (int q = 0; q < 4; ++q){
        float yv = (q==0)?y4.x:(q==1)?y4.y:(q==2)?y4.z:y4.w;
        const int j = j4*4 + q;
        #pragma unroll
        for (int t = 0; t < 8; ++t) acc[t] += yv * Wm1[j*64 + k8s + t];
      }
    }
    float* hdst = (wu < 4) ? rowS : rowL;   // k8s: 0..24 -> b32 ; 32..56 -> b64
    float o[8];
    #pragma unroll
    for (int t = 0; t < 8; ++t) o[t] = tanh_fast(acc[t]*s_s32);
    *(float4*)&hdst[k8s]     = make_float4(o[0], o[1], o[2], o[3]);
    *(float4*)&hdst[k8s + 4] = make_float4(o[4], o[5], o[6], o[7]);
  }
  __syncthreads();

  // ---- L5: g[32] = tanh(h @ Wm2 * s_s64); partial dot with Wm3 -> b64[wu] ----
  {
    float acc[4];
    #pragma unroll
    for (int t = 0; t < 4; ++t) acc[t] = 0.f;
    #pragma unroll 4
    for (int j4 = 0; j4 < 8; ++j4){            // h lo: b32[0,32)
      float4 h4 = *(const float4*)&rowS[j4*4];
      #pragma unroll
      for (int q = 0; q < 4; ++q){
        float hv = (q==0)?h4.x:(q==1)?h4.y:(q==2)?h4.z:h4.w;
        const int j = j4*4 + q;
        #pragma unroll
        for (int t = 0; t < 4; ++t) acc[t] += hv * Wm2[j*32 + k4 + t];
      }
    }
    #pragma unroll 4
    for (int j4 = 0; j4 < 8; ++j4){            // h hi: b64[32,64)
      float4 h4 = *(const float4*)&rowL[32 + j4*4];
      #pragma unroll
      for (int q = 0; q < 4; ++q){
        float hv = (q==0)?h4.x:(q==1)?h4.y:(q==2)?h4.z:h4.w;
        const int j = 32 + j4*4 + q;
        #pragma unroll
        for (int t = 0; t < 4; ++t) acc[t] += hv * Wm2[j*32 + k4 + t];
      }
    }
    float part = 0.f;
    #pragma unroll
    for (int t = 0; t < 4; ++t) part += tanh_fast(acc[t]*s_s64) * Wm3[k4 + t];
    rowL[wu] = part;   // b64[0,32) = y2, dead after L4 reads
  }
  __syncthreads();

  if (wu == 0 && valid){
    float4 p0 = *(const float4*)&rowL[0];
    float4 p1 = *(const float4*)&rowL[4];
    out[n] = (p0.x + p0.y + p0.z + p0.w + p1.x + p1.y + p1.z + p1.w) * s_s32;
  }
}

extern "C" void kernel_launch(void* const* d_in, const int* in_sizes, int n_in,
                              void* d_out, int out_size, void* d_ws, size_t ws_size,
                              hipStream_t stream) {
  const float* coords   = (const float*)d_in[0];
  const int*   species  = (const int*)  d_in[1];
  const int*   ei       = (const int*)  d_in[2];
  const float* Wna      = (const float*)d_in[4];
  const float* Wlin1    = (const float*)d_in[5];
  const float* Wr1      = (const float*)d_in[6];
  const float* Wr2      = (const float*)d_in[7];
  const float* Wr3      = (const float*)d_in[8];
  const float* W2s      = (const float*)d_in[9];
  const float* Wsc      = (const float*)d_in[11];
  const float* Wfin     = (const float*)d_in[12];
  const float* Wr       = (const float*)d_in[13];
  const float* Wm1      = (const float*)d_in[14];
  const float* Wm2      = (const float*)d_in[15];
  const float* Wm3      = (const float*)d_in[16];
  float* out = (float*)d_out;

  const int N = in_sizes[1];
  const int E = in_sizes[2] / 2;

  char* ws = (char*)d_ws;
  size_t offSC  = 0;                                 // sctab 1024B
  size_t offTAB = offSC + 1024;                      // tab (NTAB+2)*128 f32 (~1.05MB)
  size_t offH   = offTAB + (size_t)(NTAB+2)*128*4;   // hist [N] int
  size_t offP   = offH + (size_t)N*4;                // pay  [N*DEGCAP] u32 (12.8MB)
  size_t offPK  = offP + (size_t)N*DEGCAP*4;         // packed [N] float4 (1.6MB)

  float*    sctab = (float*)(ws + offSC);
  float*    tab   = (float*)(ws + offTAB);
  int*      hist  = (int*)  (ws + offH);
  unsigned* pay   = (unsigned*)(ws + offP);
  float4*   packed= (float4*)(ws + offPK);

  hipMemsetAsync(hist, 0, (size_t)N*4, stream);

  int nTab   = (NTAB + 1 + 255) / 256;               // 9 tab blocks
  int nEdge  = (E + 255) / 256;
  k_pack<<<(N + 255) / 256, 256, 0, stream>>>(coords, species, packed, N);
  k_fused<<<nTab + 1 + nEdge, 256, 0, stream>>>(packed, ei, hist, pay, E,
                                                Wna, Wlin1, Wsc, Wr1, Wr2, Wr3,
                                                sctab, tab, nTab);
  k_tail<<<(N + 63) / 64, 512, 0, stream>>>(hist, pay, tab, sctab, species,
                                            W2s, Wfin, Wr, Wm1, Wm2, Wm3, out, N);
}

// Round 25
// 96.968 us; speedup vs baseline: 1.4303x; 1.0443x over previous
//
#include <hip/hip_runtime.h>
#include <math.h>

#define RMAX 4.0f
#define NTAB 2048    // intervals over [0,4); lerp err ~ (4/NTAB)^2/8 ~ 5e-7 rel
#define DEGCAP 32    // live in-degree ~Poisson(6.9); P(>32)~1e-14 -> exact
#define TR64 68      // 64-wide LDS row stride: 272B = 16B-aligned
#define TR32 36      // 32-wide LDS row stride: 144B = 16B-aligned

__device__ __forceinline__ float rcp_fast(float x){
  return __builtin_amdgcn_rcpf(x);   // raw v_rcp_f32, ~1 ulp
}
__device__ __forceinline__ float tanh_fast(float x){
  float e = __expf(2.0f * x);
  return 1.0f - 2.0f * rcp_fast(e + 1.0f);
}
__device__ __forceinline__ float normact(float s){
  float ns = fabsf(s);
  return s * tanh_fast(ns) * rcp_fast(ns + 1e-8f);
}

// ---------------- fused: radial table | sctab | edge build ----------------
// blocks [0,nTab): tab rows (long-running, dispatched first -> overlap edges)
// block  nTab:     sctab
// blocks >nTab:    bucketed edge build (pay[d*DEGCAP+slot] = r|species(src))
// Direct coords/species reads (round-11 form, measured == packed reads) ->
// no k_pack launch, no packed buffer.
__global__ void __launch_bounds__(256) k_fused(
    const float* __restrict__ coords, const int* __restrict__ species,
    const int* __restrict__ ei,
    int* __restrict__ hist, unsigned* __restrict__ pay, int E,
    const float* __restrict__ Wna, const float* __restrict__ Wlin1,
    const float* __restrict__ Wsc,
    const float* __restrict__ Wr1, const float* __restrict__ Wr2,
    const float* __restrict__ Wr3,
    float* __restrict__ sctab, float* __restrict__ tab, int nTab){
  __shared__ float sW1[8*64];
  __shared__ float sW2T[64*64];
  __shared__ float sW3[64*32];
  __shared__ float sX1[4*32];
  int b = blockIdx.x;
  int t = threadIdx.x;

  if (b > nTab){                        // ---- edges ----
    int i = (b - nTab - 1) * 256 + t;
    if (i >= E) return;
    int s = ei[i], d = ei[E + i];
    float3 cs = *(const float3*)(coords + 3*s);
    float3 cd = *(const float3*)(coords + 3*d);
    float dx = cd.x - cs.x, dy = cd.y - cs.y, dz = cd.z - cs.z;
    float r2 = dx*dx + dy*dy + dz*dz + 1e-8f;
    if (r2 >= RMAX*RMAX) return;        // fcut=0 -> msg exactly 0
    float r = sqrtf(r2);
    unsigned u = (__float_as_uint(r) & ~3u) | (unsigned)species[s];
    int pos = atomicAdd(&hist[d], 1);
    if (pos < DEGCAP) pay[(size_t)d * DEGCAP + pos] = u;
    return;
  }
  if (b == nTab){                       // ---- sctab ----
    if (t < 256){
      int c = t >> 6, k = t & 63;
      float acc = 0.f;
      for (int i = 0; i < 32; ++i) acc += Wna[c*32+i] * Wsc[(i*4+c)*64+k];
      sctab[t] = acc * (0.5f * 0.08838834764831843f);
    }
    return;
  }
  // ---- radial table ----
  for (int i = t; i < 512; i += 256) sW1[i] = Wr1[i] * 0.3535533905932738f;
  for (int i = t; i < 4096; i += 256){ int rr = i >> 6, cc = i & 63; sW2T[cc*64+rr] = Wr2[i] * 0.125f; }
  for (int i = t; i < 2048; i += 256){ int rr = i >> 5, cc = i & 31; sW3[i] = Wr3[rr*64+cc] * 0.125f; }
  if (t < 128){                         // x1tab inline
    int c = t >> 5, j = t & 31;
    float acc = 0.f;
    for (int i = 0; i < 32; ++i) acc += Wna[c*32+i] * Wlin1[i*32+j];
    sX1[t] = acc * (0.5f * 0.17677669529663687f);
  }
  __syncthreads();
  int i = b * 256 + t;
  if (i > NTAB) return;
  float r = fmaxf((float)i * (RMAX / (float)NTAB), 1e-6f);

  float u = r * 0.25f;
  float u2 = u*u, u4 = u2*u2, u6 = u4*u2;
  float fc = 1.0f + u6 * (-28.0f + u * (48.0f - 21.0f * u));
  float pref = 0.5f * rcp_fast(r) * fc;
  float ea[8];
  #pragma unroll
  for (int k = 1; k <= 8; ++k) ea[k-1] = __sinf(0.78539816339744831f * r * (float)k) * pref;

  float h1[64];
  #pragma unroll
  for (int j = 0; j < 64; j += 4){
    float ax = 0.f, ay = 0.f, az = 0.f, aw = 0.f;
    #pragma unroll
    for (int k = 0; k < 8; ++k){
      const float4 w4 = *(const float4*)&sW1[k*64 + j];
      ax += ea[k]*w4.x; ay += ea[k]*w4.y; az += ea[k]*w4.z; aw += ea[k]*w4.w;
    }
    h1[j]   = tanh_fast(ax); h1[j+1] = tanh_fast(ay);
    h1[j+2] = tanh_fast(az); h1[j+3] = tanh_fast(aw);
  }

  float wsx[8], wsy[8], wsz[8], wsw[8];
  #pragma unroll
  for (int g = 0; g < 8; ++g){ wsx[g]=0.f; wsy[g]=0.f; wsz[g]=0.f; wsw[g]=0.f; }
  for (int j = 0; j < 64; ++j){
    float ax = 0.f, ay = 0.f, az = 0.f, aw = 0.f;
    #pragma unroll
    for (int k = 0; k < 64; k += 4){
      const float4 w4 = *(const float4*)&sW2T[j*64 + k];
      ax += h1[k]*w4.x; ay += h1[k+1]*w4.y; az += h1[k+2]*w4.z; aw += h1[k+3]*w4.w;
    }
    float tj = tanh_fast(ax + ay + az + aw);
    #pragma unroll
    for (int g = 0; g < 8; ++g){
      const float4 w4 = *(const float4*)&sW3[j*32 + g*4];
      wsx[g] += tj*w4.x; wsy[g] += tj*w4.y; wsz[g] += tj*w4.z; wsw[g] += tj*w4.w;
    }
  }

  #pragma unroll
  for (int c = 0; c < 4; ++c){
    float* row = tab + ((size_t)i*4 + c)*32;
    #pragma unroll
    for (int g = 0; g < 8; ++g){
      const float4 xv = *(const float4*)&sX1[c*32 + g*4];
      row[g*4+0] = wsx[g]*xv.x;
      row[g*4+1] = wsy[g]*xv.y;
      row[g*4+2] = wsz[g]*xv.z;
      row[g*4+3] = wsw[g]*xv.w;
    }
  }
}

// ---------------- fused gather + node tail: 64 nodes/block, 8-wave k-split ----
// k_tail structure frozen (round-23 b128 form): wall invariant ~54us across
// five structures; VALUBusy 55%, occupancy 57%. Serial phase-latency floor.
__global__ void __launch_bounds__(512, 8) k_tail(
    const int* __restrict__ hist, const unsigned* __restrict__ pay,
    const float* __restrict__ tab, const float* __restrict__ sctab,
    const int* __restrict__ species,
    const float* __restrict__ W2s, const float* __restrict__ Wfin,
    const float* __restrict__ Wr,  const float* __restrict__ Wm1,
    const float* __restrict__ Wm2, const float* __restrict__ Wm3,
    float* __restrict__ out, int N){
  const float s_16s32 = 0.0625f * 0.17677669529663687f;
  const float s_s64   = 0.125f;
  const float s_s32   = 0.17677669529663687f;
  __shared__ float b64[64 * TR64];   // 17.41 KB
  __shared__ float b32[64 * TR32];   // 9.22 KB

  // ---- Phase G: gather 64 nodes with 512 threads (8 lanes/node) ----
  {
    int nb  = threadIdx.x >> 3;      // node-in-block 0..63
    int sub = threadIdx.x & 7;       // owns comps [sub*4, sub*4+4)
    int ng  = blockIdx.x * 64 + nb;
    int ngc = min(ng, N - 1);
    float4 accA = make_float4(0.f, 0.f, 0.f, 0.f);
    int cnt = min(hist[ngc], DEGCAP);
    const unsigned* prow = pay + (size_t)ngc * DEGCAP;
    const uint4* p4 = (const uint4*)prow;
    uint4 u0 = p4[0], u1 = p4[1];    // always in-bounds (DEGCAP slots exist)
    #define GSTEP(UVAL, EIDX)                                                  \
      if ((EIDX) < cnt){                                                       \
        unsigned uu = (UVAL);                                                  \
        int ccc = (int)(uu & 3u);                                              \
        float r = __uint_as_float(uu & ~3u);                                   \
        float tt = r * ((float)NTAB / RMAX);                                   \
        int i0 = min((int)tt, NTAB - 1);                                       \
        float f = tt - (float)i0;                                              \
        const float4* r0 = (const float4*)(tab + ((size_t)i0*4 + ccc)*32) + sub; \
        float4 p = r0[0], q = r0[32];                                          \
        accA.x += p.x + f*(q.x - p.x);                                         \
        accA.y += p.y + f*(q.y - p.y);                                         \
        accA.z += p.z + f*(q.z - p.z);                                         \
        accA.w += p.w + f*(q.w - p.w);                                         \
      }
    GSTEP(u0.x, 0) GSTEP(u0.y, 1) GSTEP(u0.z, 2) GSTEP(u0.w, 3)
    GSTEP(u1.x, 4) GSTEP(u1.y, 5) GSTEP(u1.z, 6) GSTEP(u1.w, 7)
    for (int e = 8; e < cnt; ++e){ GSTEP(prow[e], e) }
    #undef GSTEP
    *(float4*)&b32[nb * TR32 + sub * 4] = accA;
  }
  __syncthreads();

  // ---- Tail: lane = node-in-block; wave wu owns its k-slice ----
  int lane = threadIdx.x & 63;
  int wu   = __builtin_amdgcn_readfirstlane(threadIdx.x >> 6);  // 0..7, SGPR
  int n    = blockIdx.x * 64 + lane;
  bool valid = n < N;
  int nc  = valid ? n : (N - 1);
  int c   = species[nc];
  int k8s = wu * 8;    // 64-wide slice offset
  int k4  = wu * 4;    // 32-wide slice offset
  float* rowL = &b64[lane * TR64];
  float* rowS = &b32[lane * TR32];

  // ---- L1: S[64] = normact(a @ W2s * s + sctab[c]); wave owns [k8s,k8s+8) ----
  {
    float acc[8];
    #pragma unroll
    for (int t = 0; t < 8; ++t) acc[t] = 0.f;
    #pragma unroll 4
    for (int j4 = 0; j4 < 8; ++j4){
      float4 a4 = *(const float4*)&rowS[j4*4];
      #pragma unroll
      for (int q = 0; q < 4; ++q){
        float av = (q==0)?a4.x:(q==1)?a4.y:(q==2)?a4.z:a4.w;
        const int j = j4*4 + q;
        #pragma unroll
        for (int t = 0; t < 8; ++t) acc[t] += av * W2s[j*64 + k8s + t];
      }
    }
    float o[8];
    #pragma unroll
    for (int t = 0; t < 8; ++t)
      o[t] = normact(acc[t]*s_16s32 + sctab[c*64 + k8s + t]);
    *(float4*)&rowL[k8s]     = make_float4(o[0], o[1], o[2], o[3]);
    *(float4*)&rowL[k8s + 4] = make_float4(o[4], o[5], o[6], o[7]);
  }
  __syncthreads();

  // ---- L2: y[32] = normact(S @ Wfin * s_s64); wave owns [k4,k4+4) ----
  {
    float acc[4];
    #pragma unroll
    for (int t = 0; t < 4; ++t) acc[t] = 0.f;
    #pragma unroll 4
    for (int j4 = 0; j4 < 16; ++j4){
      float4 s4 = *(const float4*)&rowL[j4*4];
      #pragma unroll
      for (int q = 0; q < 4; ++q){
        float sv = (q==0)?s4.x:(q==1)?s4.y:(q==2)?s4.z:s4.w;
        const int j = j4*4 + q;
        #pragma unroll
        for (int t = 0; t < 4; ++t) acc[t] += sv * Wfin[j*32 + k4 + t];
      }
    }
    *(float4*)&rowS[k4] = make_float4(normact(acc[0]*s_s64), normact(acc[1]*s_s64),
                                      normact(acc[2]*s_s64), normact(acc[3]*s_s64));
  }
  __syncthreads();

  // ---- L3: y2[32] = y + normact(y @ Wr * s_s32); y2 -> b64[0,32) ----
  {
    float acc[4];
    #pragma unroll
    for (int t = 0; t < 4; ++t) acc[t] = 0.f;
    #pragma unroll 4
    for (int j4 = 0; j4 < 8; ++j4){
      float4 y4 = *(const float4*)&rowS[j4*4];
      #pragma unroll
      for (int q = 0; q < 4; ++q){
        float yv = (q==0)?y4.x:(q==1)?y4.y:(q==2)?y4.z:y4.w;
        const int j = j4*4 + q;
        #pragma unroll
        for (int t = 0; t < 4; ++t) acc[t] += yv * Wr[j*32 + k4 + t];
      }
    }
    float4 ysave = *(const float4*)&rowS[k4];
    *(float4*)&rowL[k4] = make_float4(ysave.x + normact(acc[0]*s_s32),
                                      ysave.y + normact(acc[1]*s_s32),
                                      ysave.z + normact(acc[2]*s_s32),
                                      ysave.w + normact(acc[3]*s_s32));
  }
  __syncthreads();

  // ---- L4: h[64] = tanh(y2 @ Wm1 * s_s32); waves 0-3 -> b32, 4-7 -> b64[32,64) ----
  {
    float acc[8];
    #pragma unroll
    for (int t = 0; t < 8; ++t) acc[t] = 0.f;
    #pragma unroll 4
    for (int j4 = 0; j4 < 8; ++j4){
      float4 y4 = *(const float4*)&rowL[j4*4];
      #pragma unroll
      for (int q = 0; q < 4; ++q){
        float yv = (q==0)?y4.x:(q==1)?y4.y:(q==2)?y4.z:y4.w;
        const int j = j4*4 + q;
        #pragma unroll
        for (int t = 0; t < 8; ++t) acc[t] += yv * Wm1[j*64 + k8s + t];
      }
    }
    float* hdst = (wu < 4) ? rowS : rowL;   // k8s: 0..24 -> b32 ; 32..56 -> b64
    float o[8];
    #pragma unroll
    for (int t = 0; t < 8; ++t) o[t] = tanh_fast(acc[t]*s_s32);
    *(float4*)&hdst[k8s]     = make_float4(o[0], o[1], o[2], o[3]);
    *(float4*)&hdst[k8s + 4] = make_float4(o[4], o[5], o[6], o[7]);
  }
  __syncthreads();

  // ---- L5: g[32] = tanh(h @ Wm2 * s_s64); partial dot with Wm3 -> b64[wu] ----
  {
    float acc[4];
    #pragma unroll
    for (int t = 0; t < 4; ++t) acc[t] = 0.f;
    #pragma unroll 4
    for (int j4 = 0; j4 < 8; ++j4){            // h lo: b32[0,32)
      float4 h4 = *(const float4*)&rowS[j4*4];
      #pragma unroll
      for (int q = 0; q < 4; ++q){
        float hv = (q==0)?h4.x:(q==1)?h4.y:(q==2)?h4.z:h4.w;
        const int j = j4*4 + q;
        #pragma unroll
        for (int t = 0; t < 4; ++t) acc[t] += hv * Wm2[j*32 + k4 + t];
      }
    }
    #pragma unroll 4
    for (int j4 = 0; j4 < 8; ++j4){            // h hi: b64[32,64)
      float4 h4 = *(const float4*)&rowL[32 + j4*4];
      #pragma unroll
      for (int q = 0; q < 4; ++q){
        float hv = (q==0)?h4.x:(q==1)?h4.y:(q==2)?h4.z:h4.w;
        const int j = 32 + j4*4 + q;
        #pragma unroll
        for (int t = 0; t < 4; ++t) acc[t] += hv * Wm2[j*32 + k4 + t];
      }
    }
    float part = 0.f;
    #pragma unroll
    for (int t = 0; t < 4; ++t) part += tanh_fast(acc[t]*s_s64) * Wm3[k4 + t];
    rowL[wu] = part;   // b64[0,32) = y2, dead after L4 reads
  }
  __syncthreads();

  if (wu == 0 && valid){
    float4 p0 = *(const float4*)&rowL[0];
    float4 p1 = *(const float4*)&rowL[4];
    out[n] = (p0.x + p0.y + p0.z + p0.w + p1.x + p1.y + p1.z + p1.w) * s_s32;
  }
}

extern "C" void kernel_launch(void* const* d_in, const int* in_sizes, int n_in,
                              void* d_out, int out_size, void* d_ws, size_t ws_size,
                              hipStream_t stream) {
  const float* coords   = (const float*)d_in[0];
  const int*   species  = (const int*)  d_in[1];
  const int*   ei       = (const int*)  d_in[2];
  const float* Wna      = (const float*)d_in[4];
  const float* Wlin1    = (const float*)d_in[5];
  const float* Wr1      = (const float*)d_in[6];
  const float* Wr2      = (const float*)d_in[7];
  const float* Wr3      = (const float*)d_in[8];
  const float* W2s      = (const float*)d_in[9];
  const float* Wsc      = (const float*)d_in[11];
  const float* Wfin     = (const float*)d_in[12];
  const float* Wr       = (const float*)d_in[13];
  const float* Wm1      = (const float*)d_in[14];
  const float* Wm2      = (const float*)d_in[15];
  const float* Wm3      = (const float*)d_in[16];
  float* out = (float*)d_out;

  const int N = in_sizes[1];
  const int E = in_sizes[2] / 2;

  char* ws = (char*)d_ws;
  size_t offSC  = 0;                                 // sctab 1024B
  size_t offTAB = offSC + 1024;                      // tab (NTAB+2)*128 f32 (~1.05MB)
  size_t offH   = offTAB + (size_t)(NTAB+2)*128*4;   // hist [N] int
  size_t offP   = offH + (size_t)N*4;                // pay  [N*DEGCAP] u32 (12.8MB)

  float*    sctab = (float*)(ws + offSC);
  float*    tab   = (float*)(ws + offTAB);
  int*      hist  = (int*)  (ws + offH);
  unsigned* pay   = (unsigned*)(ws + offP);

  hipMemsetAsync(hist, 0, (size_t)N*4, stream);

  int nTab   = (NTAB + 1 + 255) / 256;               // 9 tab blocks
  int nEdge  = (E + 255) / 256;
  k_fused<<<nTab + 1 + nEdge, 256, 0, stream>>>(coords, species, ei, hist, pay, E,
                                                Wna, Wlin1, Wsc, Wr1, Wr2, Wr3,
                                                sctab, tab, nTab);
  k_tail<<<(N + 63) / 64, 512, 0, stream>>>(hist, pay, tab, sctab, species,
                                            W2s, Wfin, Wr, Wm1, Wm2, Wm3, out, N);
}